// Round 7
// baseline (120.615 us; speedup 1.0000x reference)
//
#include <hip/hip_runtime.h>
#include <math.h>

#define EPSF 1.1920929e-07f

typedef float f4 __attribute__((ext_vector_type(4)));

__device__ __forceinline__ float sigmoid_fast(float v) {
    return 1.0f / (1.0f + __expf(-v));
}
__device__ __forceinline__ float tanh_fast(float x) {
    float ax = fabsf(x);
    float e  = __expf(-2.0f * ax);          // in (0,1], never overflows
    float t  = (1.0f - e) / (1.0f + e);
    return copysignf(t, x);
}
__device__ __forceinline__ float gauss_fast(float i, float m, float sg) {
    float d = (i - m) / sg;
    return __expf(-0.5f * d * d);
}

// ---------------------------------------------------------------------------
// Fully fused, one (b,c,x) plane of 64x64 per block (8192 blocks, 256 thr).
// ZERO barriers, ZERO LDS: each wave redundantly computes the tiny MLP with
// lane-parallel dots + __shfl broadcasts, each thread derives its own 9
// gaussian coefficients in registers. The 4 NT x-loads issue at the top and
// stay in flight under the whole preamble (no barrier -> no vmcnt drain).
// ---------------------------------------------------------------------------
__global__ void __launch_bounds__(256, 8) fused_kernel(
        const float* __restrict__ xin, const float* __restrict__ tab,
        const float* __restrict__ w1,  const float* __restrict__ b1,
        const float* __restrict__ w2,  const float* __restrict__ b2,
        const float* __restrict__ wp,  const float* __restrict__ bp,
        const float* __restrict__ wsg, const float* __restrict__ bsg,
        float* __restrict__ out, int out_last)
{
    const int tid  = threadIdx.x;
    const int lane = tid & 63;
    const int blk  = blockIdx.x;       // b*64*64 + c*64 + x
    const int bc   = blk >> 6;
    const int xi   = blk & 63;
    const int b    = bc >> 6;
    const int c    = bc & 63;

    // ---- issue the block's entire read set immediately (stays in flight) ----
    const f4* x4 = (const f4*)(xin + (size_t)blk * 4096);
    f4*       o4 = (f4*)(out + (size_t)blk * 4096);
    f4 x0 = __builtin_nontemporal_load(&x4[tid]);
    f4 x1 = __builtin_nontemporal_load(&x4[tid + 256]);
    f4 x2 = __builtin_nontemporal_load(&x4[tid + 512]);
    f4 x3 = __builtin_nontemporal_load(&x4[tid + 768]);

    // ---- per-wave redundant MLP (no LDS, no barriers) ----
    // layer 1: lanes 0-31 -> emb1 for b=0, lanes 32-63 -> emb1 for b=1
    const int bb = lane >> 5;
    const int j  = lane & 31;
    float e1;
    {
        float acc = b1[j];
        #pragma unroll
        for (int k = 0; k < 6; ++k) acc += tab[bb * 6 + k] * w1[j * 6 + k];
        e1 = tanh_fast(acc);
    }

    // layer 2: same lane layout; dot over emb1[bb][*] via shuffles
    float e2;
    {
        const f4* wr = (const f4*)(w2 + j * 32);
        float acc = b2[j];
        #pragma unroll
        for (int q = 0; q < 8; ++q) {
            f4 wv = wr[q];
            int base = (lane & 32) + q * 4;
            acc += wv.x * __shfl(e1, base + 0)
                 + wv.y * __shfl(e1, base + 1)
                 + wv.z * __shfl(e1, base + 2)
                 + wv.w * __shfl(e1, base + 3);
        }
        e2 = tanh_fast(acc);
    }

    // heads: 8 values for this (b,c); lane L computes head[L&7]
    // 0:scale 1:shift 2:mu_a 3:mu_b 4:mu_c 5:sa 6:sb 7:sc
    float h;
    {
        const int hidx = lane & 7;
        const float* Wh = (hidx < 5) ? wp : wsg;
        const float* Bh = (hidx < 5) ? bp : bsg;
        const int hrow  = ((hidx < 5) ? hidx : hidx - 5) * 64 + c;
        const f4* wr = (const f4*)(Wh + hrow * 32);
        h = Bh[hrow];
        #pragma unroll
        for (int q = 0; q < 8; ++q) {
            f4 wv = wr[q];
            int base = b * 32 + q * 4;
            h += wv.x * __shfl(e2, base + 0)
               + wv.y * __shfl(e2, base + 1)
               + wv.z * __shfl(e2, base + 2)
               + wv.w * __shfl(e2, base + 3);
        }
    }
    const float h0 = __shfl(h, 0), h1 = __shfl(h, 1), h2 = __shfl(h, 2),
                h3 = __shfl(h, 3), h4 = __shfl(h, 4), h5 = __shfl(h, 5),
                h6 = __shfl(h, 6), h7 = __shfl(h, 7);

    // per-thread gaussian coefficients (all in registers)
    const float m_a = tanh_fast(h2) * 32.0f + 31.5f;
    const float m_b = tanh_fast(h3) * 32.0f + 31.5f;
    const float m_c = tanh_fast(h4) * 32.0f + 31.5f;
    const float s_a = sigmoid_fast(h5) * 3.5f + EPSF;
    const float s_b = sigmoid_fast(h6) * 3.5f + EPSF;
    const float s_c = sigmoid_fast(h7) * 3.5f + EPSF;

    const float pv = (1.0f - h0) * gauss_fast((float)xi, m_a, s_a);
    const float sh = h1;

    const int yb = tid >> 4;
    const int z0 = (tid & 15) << 2;
    f4 vz;
    vz.x = gauss_fast((float)(z0 + 0), m_c, s_c);
    vz.y = gauss_fast((float)(z0 + 1), m_c, s_c);
    vz.z = gauss_fast((float)(z0 + 2), m_c, s_c);
    vz.w = gauss_fast((float)(z0 + 3), m_c, s_c);

    const f4 cw0 = vz * (pv * gauss_fast((float)(yb +  0), m_b, s_b));
    const f4 cw1 = vz * (pv * gauss_fast((float)(yb + 16), m_b, s_b));
    const f4 cw2 = vz * (pv * gauss_fast((float)(yb + 32), m_b, s_b));
    const f4 cw3 = vz * (pv * gauss_fast((float)(yb + 48), m_b, s_b));
    const f4 shv = {sh, sh, sh, sh};

    // ---- l2 scalar: block 0, wave 0 only (shuffle-reduce, no barrier) ----
    if (blk == 0 && tid < 64) {
        float tot = 0.0f;
        #pragma unroll
        for (int q = 0; q < 5; ++q) {
            float ss = 0.0f;
            #pragma unroll
            for (int half = 0; half < 2; ++half) {
                int rr  = half * 64 + lane;        // 0..127
                int bbq = rr >> 6, cc = rr & 63;
                const float* W  = (q < 2) ? wp  : wsg;
                const float* Bv = (q < 2) ? bp  : bsg;
                int row = ((q < 2) ? q : (q - 2)) * 64 + cc;
                const f4* wr = (const f4*)(W + row * 32);
                float a = Bv[row];
                #pragma unroll
                for (int u = 0; u < 8; ++u) {
                    f4 wv = wr[u];
                    int base = bbq * 32 + u * 4;
                    a += wv.x * __shfl(e2, base + 0)
                       + wv.y * __shfl(e2, base + 1)
                       + wv.z * __shfl(e2, base + 2)
                       + wv.w * __shfl(e2, base + 3);
                }
                if (q >= 2) a = sigmoid_fast(a);
                ss += a * a;
            }
            #pragma unroll
            for (int off = 32; off > 0; off >>= 1) ss += __shfl_xor(ss, off);
            tot += sqrtf(ss);
        }
        if (lane == 0) out[out_last] = tot;
    }

    // ---- streaming tail: multiply-add and store ----
    __builtin_nontemporal_store(cw0 * x0 + shv, &o4[tid]);
    __builtin_nontemporal_store(cw1 * x1 + shv, &o4[tid + 256]);
    __builtin_nontemporal_store(cw2 * x2 + shv, &o4[tid + 512]);
    __builtin_nontemporal_store(cw3 * x3 + shv, &o4[tid + 768]);
}

// ---------------------------------------------------------------------------
extern "C" void kernel_launch(void* const* d_in, const int* in_sizes, int n_in,
                              void* d_out, int out_size, void* d_ws, size_t ws_size,
                              hipStream_t stream)
{
    const float* x   = (const float*)d_in[0];
    const float* tab = (const float*)d_in[1];
    const float* w1  = (const float*)d_in[2];
    const float* b1  = (const float*)d_in[3];
    const float* w2  = (const float*)d_in[4];
    const float* b2  = (const float*)d_in[5];
    const float* wp  = (const float*)d_in[6];
    const float* bp  = (const float*)d_in[7];
    const float* wsg = (const float*)d_in[8];
    const float* bsg = (const float*)d_in[9];

    float* out = (float*)d_out;

    fused_kernel<<<2 * 64 * 64, 256, 0, stream>>>(
        x, tab, w1, b1, w2, b2, wp, bp, wsg, bsg, out, out_size - 1);
}

// Round 8
// 53.615 us; speedup vs baseline: 2.2497x; 2.2497x over previous
//
#include <hip/hip_runtime.h>
#include <math.h>

#define EPSF 1.1920929e-07f

typedef float f4 __attribute__((ext_vector_type(4)));

__device__ __forceinline__ float sigmoidf_(float v) { return 1.0f / (1.0f + expf(-v)); }

// ---------------------------------------------------------------------------
// Setup: 129 blocks x 256 threads. Blocks 0..127 = one (b,c) each: compute
// MLP + heads, write baked tables:
//   pvt[bc*64+xi] = (1-scale)*gx[xi]    (8192 floats)
//   sht[bc]                              (128)
//   gy4T[bc*16+t] = {gy[t],gy[t+16],gy[t+32],gy[t+48]}   (f4 table)
//   gz4t[bc*16+t] = {gz[4t..4t+3]}                       (f4 table)
// Block 128 computes the l2 scalar.
// ---------------------------------------------------------------------------
__global__ void __launch_bounds__(256) setup_kernel(
        const float* __restrict__ tab,
        const float* __restrict__ w1,  const float* __restrict__ b1,
        const float* __restrict__ w2,  const float* __restrict__ b2,
        const float* __restrict__ wp,  const float* __restrict__ bp,
        const float* __restrict__ wsg, const float* __restrict__ bsg,
        float* __restrict__ pvt, float* __restrict__ sht,
        f4* __restrict__ gy4T, f4* __restrict__ gz4t,
        float* __restrict__ out, int out_last)
{
    __shared__ float emb1[2][32];
    __shared__ float emb2[2][32];
    __shared__ float head[8];
    __shared__ float gys[64], gzs[64];

    const int bc  = blockIdx.x;        // 0..128
    const int b   = (bc >> 6) & 1;
    const int c   = bc & 63;
    const int tid = threadIdx.x;

    // MLP layer 1 (both batches)
    if (tid < 64) {
        int bb = tid >> 5, j = tid & 31;
        float acc = b1[j];
        #pragma unroll
        for (int k = 0; k < 6; ++k) acc += tab[bb * 6 + k] * w1[j * 6 + k];
        emb1[bb][j] = tanhf(acc);
    }
    __syncthreads();

    // MLP layer 2
    if (tid < 64) {
        int bb = tid >> 5, j = tid & 31;
        float acc = b2[j];
        #pragma unroll
        for (int k = 0; k < 32; ++k) acc += emb1[bb][k] * w2[j * 32 + k];
        emb2[bb][j] = tanhf(acc);
    }
    __syncthreads();

    if (bc == 128) {
        // l2 = sum of 5 frobenius norms
        __shared__ float sq[5][128];
        for (int t = tid; t < 640; t += 256) {
            int q = t / 128, r = t % 128;
            int bb = r >> 6, cc = r & 63;
            const float* W  = (q < 2) ? wp  : wsg;
            const float* Bv = (q < 2) ? bp  : bsg;
            int row = ((q < 2) ? q : (q - 2)) * 64 + cc;
            float acc = Bv[row];
            #pragma unroll
            for (int k = 0; k < 32; ++k) acc += emb2[bb][k] * W[row * 32 + k];
            if (q >= 2) acc = sigmoidf_(acc);
            sq[q][r] = acc * acc;
        }
        __syncthreads();
        if (tid == 0) {
            float tot = 0.0f;
            for (int q = 0; q < 5; ++q) {
                float ssum = 0.0f;
                for (int i = 0; i < 128; ++i) ssum += sq[q][i];
                tot += sqrtf(ssum);
            }
            out[out_last] = tot;
        }
        return;
    }

    // heads for this (b,c): 0:scale 1:shift 2:mu_a 3:mu_b 4:mu_c 5:sa 6:sb 7:sc
    if (tid < 8) {
        const float* W  = (tid < 5) ? wp  : wsg;
        const float* Bv = (tid < 5) ? bp  : bsg;
        int row = ((tid < 5) ? tid : (tid - 5)) * 64 + c;
        float acc = Bv[row];
        #pragma unroll
        for (int k = 0; k < 32; ++k) acc += emb2[b][k] * W[row * 32 + k];
        head[tid] = acc;
    }
    __syncthreads();

    // gaussian tables into LDS
    if (tid < 64) {
        float m  = tanhf(head[3]) * 32.0f + 31.5f;
        float sg = sigmoidf_(head[6]) * 3.5f + EPSF;
        float d  = ((float)tid - m) / sg;
        gys[tid] = expf(-0.5f * d * d);
    } else if (tid < 128) {
        int i = tid - 64;
        float m  = tanhf(head[4]) * 32.0f + 31.5f;
        float sg = sigmoidf_(head[7]) * 3.5f + EPSF;
        float d  = ((float)i - m) / sg;
        gzs[i] = expf(-0.5f * d * d);
    }
    __syncthreads();

    // write baked tables
    if (tid < 64) {
        float m  = tanhf(head[2]) * 32.0f + 31.5f;
        float sg = sigmoidf_(head[5]) * 3.5f + EPSF;
        float d  = ((float)tid - m) / sg;
        pvt[bc * 64 + tid] = (1.0f - head[0]) * expf(-0.5f * d * d);
    } else if (tid < 80) {
        int t = tid - 64;
        f4 v = {gys[t], gys[t + 16], gys[t + 32], gys[t + 48]};
        gy4T[bc * 16 + t] = v;
    } else if (tid < 96) {
        int t = tid - 80;
        f4 v = {gzs[4 * t], gzs[4 * t + 1], gzs[4 * t + 2], gzs[4 * t + 3]};
        gz4t[bc * 16 + t] = v;
    } else if (tid == 96) {
        sht[bc] = head[1];
    }
}

// ---------------------------------------------------------------------------
// Apply: one (b,c,x) plane per block. Preamble = 4 independent L2-hot loads.
// Body = plain load -> fma -> store, matching the 6.29 TB/s copy ubench.
// ---------------------------------------------------------------------------
__global__ void __launch_bounds__(256) apply_kernel(
        const float* __restrict__ xin,
        const float* __restrict__ pvt, const float* __restrict__ sht,
        const f4* __restrict__ gy4T, const f4* __restrict__ gz4t,
        float* __restrict__ out)
{
    const int blk = blockIdx.x;        // b*64*64 + c*64 + x
    const int bc  = blk >> 6;
    const int tid = threadIdx.x;

    const f4* x4 = (const f4*)(xin + (size_t)blk * 4096);
    f4*       o4 = (f4*)(out + (size_t)blk * 4096);

    f4 x0 = x4[tid];
    f4 x1 = x4[tid + 256];
    f4 x2 = x4[tid + 512];
    f4 x3 = x4[tid + 768];

    const float pv  = pvt[blk];
    const float sh  = sht[bc];
    const f4    gyv = gy4T[bc * 16 + (tid >> 4)];
    const f4    vz  = gz4t[bc * 16 + (tid & 15)];

    const f4 w0 = vz * (pv * gyv.x);
    const f4 w1 = vz * (pv * gyv.y);
    const f4 w2 = vz * (pv * gyv.z);
    const f4 w3 = vz * (pv * gyv.w);
    const f4 shv = {sh, sh, sh, sh};

    o4[tid]       = w0 * x0 + shv;
    o4[tid + 256] = w1 * x1 + shv;
    o4[tid + 512] = w2 * x2 + shv;
    o4[tid + 768] = w3 * x3 + shv;
}

// ---------------------------------------------------------------------------
extern "C" void kernel_launch(void* const* d_in, const int* in_sizes, int n_in,
                              void* d_out, int out_size, void* d_ws, size_t ws_size,
                              hipStream_t stream)
{
    const float* x   = (const float*)d_in[0];
    const float* tab = (const float*)d_in[1];
    const float* w1  = (const float*)d_in[2];
    const float* b1  = (const float*)d_in[3];
    const float* w2  = (const float*)d_in[4];
    const float* b2  = (const float*)d_in[5];
    const float* wp  = (const float*)d_in[6];
    const float* bp  = (const float*)d_in[7];
    const float* wsg = (const float*)d_in[8];
    const float* bsg = (const float*)d_in[9];

    float* ws   = (float*)d_ws;
    float* pvt  = ws;                  // 8192
    float* sht  = ws + 8192;           // 128
    f4*    gy4T = (f4*)(ws + 8320);    // 128*16 f4 = 8192 floats
    f4*    gz4t = (f4*)(ws + 16512);   // 8192 floats

    float* out = (float*)d_out;

    setup_kernel<<<129, 256, 0, stream>>>(tab, w1, b1, w2, b2, wp, bp, wsg, bsg,
                                          pvt, sht, gy4T, gz4t, out, out_size - 1);

    apply_kernel<<<2 * 64 * 64, 256, 0, stream>>>(x, pvt, sht, gy4T, gz4t, out);
}